// Round 4
// baseline (134.751 us; speedup 1.0000x reference)
//
#include <hip/hip_runtime.h>
#include <hip/hip_bf16.h>
#include <stdint.h>

// ---------------------------------------------------------------------------
// SupervisedContrastiveLoss, B=4096, D=1024, C=32, T=0.1, eps=1e-8
// out = (1/B) * [ sum_i (log(denom_i)*W_i - posS_i) - pw*INV_T*||G||_F^2 ]
// R8: 3 dispatches. R5 geometry (128x128 upper-tri tiles, dbuf LDS) but
//     8 waves/block (512 thr): waves/SIMD 2->4 for latency hiding.
//   D1: normalize->fp8(x16) + prep partials + zero            (256 thr)
//   D2: 528 gemm tiles (XCD-swizzled, 528=8*66) + 512 G + 8 W (512 thr)
//   D3: finalize (9 blocks, done-counter writes out)          (256 thr)
// ---------------------------------------------------------------------------

typedef float f32x4 __attribute__((ext_vector_type(4)));
typedef long i64;

#define INV_T 10.0f
#define Z_SCALE (INV_T / 256.0f)   // both fp8 operands carry x16

#define GLD16(gp, lp)                                                          \
    __builtin_amdgcn_global_load_lds(                                          \
        (const __attribute__((address_space(1))) uint32_t*)(gp),               \
        (__attribute__((address_space(3))) uint32_t*)(lp), 16, 0, 0)

// workspace layout (bytes)
#define OFF_RNF8  0                         // 4096*1024 = 4194304
#define OFF_DENOM 4194304                   // 4096*4
#define OFF_POSS  (OFF_DENOM + 16384)
#define OFF_G     (OFF_POSS + 16384)        // 1024*32*4 = 131072
#define OFF_OACC  (OFF_G + 131072)          // double
#define OFF_DONE  (OFF_OACC + 16)           // int
#define ZERO_SPAN 167936                    // 41*4096 >= 163904 (zeroed region)
#define OFF_CSP   (OFF_DENOM + ZERO_SPAN)   // 32*32*4 colsum partials
#define OFF_CCP   (OFF_CSP + 4096)          // 32*32*4 histogram partials
#define OFF_W     (OFF_CCP + 4096)          // 4096*4

#define N_GEMM 528
#define N_G    512
#define N_W    8
#define N_ALL  (N_GEMM + N_G + N_W)         // 1048

// ---------------- D1: normalize -> fp8(x16) | prep partials | zero ----------
__global__ __launch_bounds__(256) void scl_stage1(const float* __restrict__ rep,
                                                  const float* __restrict__ sl,
                                                  const int* __restrict__ labels,
                                                  uint32_t* __restrict__ rnf8,
                                                  float* __restrict__ cs_part,
                                                  int* __restrict__ cc_part,
                                                  char* __restrict__ zbase) {
    int b = blockIdx.x;
    int t = threadIdx.x;
    if (b < 4096) {
        int row = b;
        const float4* src = reinterpret_cast<const float4*>(rep + (size_t)row * 1024);
        float4 v = src[t];
        float s = v.x * v.x + v.y * v.y + v.z * v.z + v.w * v.w;
#pragma unroll
        for (int m = 1; m < 64; m <<= 1) s += __shfl_xor(s, m, 64);
        __shared__ float red[4];
        if ((t & 63) == 0) red[t >> 6] = s;
        __syncthreads();
        s = red[0] + red[1] + red[2] + red[3];
        float nf = 16.0f / fmaxf(sqrtf(s), 1e-8f);   // x16 into fp8 normal range
        int p = 0;
        p = __builtin_amdgcn_cvt_pk_fp8_f32(v.x * nf, v.y * nf, p, false);
        p = __builtin_amdgcn_cvt_pk_fp8_f32(v.z * nf, v.w * nf, p, true);
        rnf8[row * 256 + t] = (uint32_t)p;
    } else if (b < 4128) {
        // prep partials: colsum of soft_labels + class histogram (128 rows/slab)
        __shared__ float part[8][32];
        __shared__ int bins[32];
        int bb = b - 4096;
        if (t < 32) bins[t] = 0;
        __syncthreads();
        if (t < 128) atomicAdd(&bins[labels[bb * 128 + t]], 1);
        int c = t & 31, rg = t >> 5;
        float s = 0.f;
#pragma unroll 4
        for (int k = 0; k < 16; ++k) {
            int i = bb * 128 + rg * 16 + k;
            s += sl[i * 32 + c];
        }
        part[rg][c] = s;
        __syncthreads();
        if (t < 32) {
            float tot = 0.f;
#pragma unroll
            for (int g = 0; g < 8; ++g) tot += part[g][t];
            cs_part[bb * 32 + t] = tot;
            cc_part[bb * 32 + t] = bins[t];
        }
    } else {
        // zero blocks: denom/posS/G/oacc/done (consumed in D2/D3)
        int zb = b - 4128;
        *(uint4*)(zbase + (size_t)zb * 4096 + t * 16) = (uint4){0, 0, 0, 0};
    }
}

// ---------------- D2: fused gemm + G + W (512 threads) ----------------------
__global__ __launch_bounds__(512, 4) void scl_main(const uint8_t* __restrict__ rnf8,
                                                   const float* __restrict__ sl,
                                                   const int* __restrict__ labels,
                                                   const float* __restrict__ cs_part,
                                                   const int* __restrict__ cc_part,
                                                   const int* __restrict__ pwp,
                                                   float* __restrict__ denom,
                                                   float* __restrict__ posS,
                                                   float* __restrict__ G,
                                                   float* __restrict__ W) {
    int tid = threadIdx.x;
    int bIdx = blockIdx.x;

    if (bIdx >= N_GEMM) {
        if (bIdx < N_GEMM + N_G) {
            // ---- G = rn^T @ SL : 16 d-blocks x 32 k-splits (512 thr) ----
            int idx = bIdx - N_GEMM;
            int dblk = idx & 15, ks = idx >> 4;
            int dq = tid >> 5, c = tid & 31;       // dq 0..15 -> 4 dims each
            int d0 = dblk * 64 + dq * 4;
            float acc[4];
#pragma unroll
            for (int j = 0; j < 4; ++j) acc[j] = 0.f;
            int i0 = ks * 128;
#pragma unroll 4
            for (int k = 0; k < 128; ++k) {
                int i = i0 + k;
                uint32_t rv = *(const uint32_t*)&rnf8[(size_t)i * 1024 + d0];
                float sv = sl[i * 32 + c];
                acc[0] += __builtin_amdgcn_cvt_f32_fp8((int)rv, 0) * sv;
                acc[1] += __builtin_amdgcn_cvt_f32_fp8((int)rv, 1) * sv;
                acc[2] += __builtin_amdgcn_cvt_f32_fp8((int)rv, 2) * sv;
                acc[3] += __builtin_amdgcn_cvt_f32_fp8((int)rv, 3) * sv;
            }
#pragma unroll
            for (int j = 0; j < 4; ++j)
                atomicAdd(&G[(d0 + j) * 32 + c], acc[j] * 0.0625f);  // undo x16
        } else {
            // ---- W[i] = (ccnt[l_i]-1) + pw*(sl_i . csum) : 8 blocks x 512 rows
            __shared__ __align__(16) float css[32];
            __shared__ int ccs[32];
            if (tid < 32) {
                float s = 0.f; int n = 0;
#pragma unroll
                for (int b = 0; b < 32; ++b) { s += cs_part[b * 32 + tid]; n += cc_part[b * 32 + tid]; }
                css[tid] = s; ccs[tid] = n;
            }
            __syncthreads();
            int bits = *pwp;
            float pw = (bits >= -(1 << 22) && bits <= (1 << 22)) ? (float)bits
                                                                 : __int_as_float(bits);
            int i = (bIdx - (N_GEMM + N_G)) * 512 + tid;
            const f32x4* sl4 = (const f32x4*)sl;
            const f32x4* cs4 = (const f32x4*)css;
            float dW = 0.f;
#pragma unroll
            for (int q = 0; q < 8; ++q) {
                f32x4 s = sl4[i * 8 + q];
                f32x4 c = cs4[q];
                dW += s[0] * c[0] + s[1] * c[1] + s[2] * c[2] + s[3] * c[3];
            }
            W[i] = (float)(ccs[labels[i]] - 1) + pw * dW;
        }
        return;
    }

    // ---- main fp8 GEMM tile (128x128, 8 waves) ----
    __shared__ __align__(16) uint8_t As[2][128 * 64];
    __shared__ __align__(16) uint8_t Bs[2][128 * 64];
    __shared__ int lblA[128], lblB[128];

    // XCD-bijective swizzle: 528 = 8*66; XCD x gets 66 contiguous tiles.
    int L = (bIdx & 7) * 66 + (bIdx >> 3);
    int bi = 0, rem = L;
    while (rem >= 32 - bi) { rem -= 32 - bi; ++bi; }
    int bj = bi + rem;
    int rowA0 = bi * 128, colB0 = bj * 128;

    if (tid < 128) lblA[tid] = labels[rowA0 + tid];
    else if (tid < 256) lblB[tid - 128] = labels[colB0 + (tid - 128)];

    int lane = tid & 63, warp = tid >> 6;          // 8 waves
    int wr = warp >> 2, wc = warp & 3;             // 2 x 4 wave grid
    int m_ = lane & 15, g = lane >> 4;

    // staging: wave w covers rows w*16..w*16+15 (one GLD16/thread per matrix)
    // lane l -> row w*16 + (l>>2), LDS slot l&3; global chunk (l&3)^((l>>3)&3)
    int r4 = lane >> 2;
    int csw = (lane & 3) ^ ((lane >> 3) & 3);
    const uint8_t* gA0 = rnf8 + (size_t)(rowA0 + warp * 16 + r4) * 1024 + csw * 16;
    const uint8_t* gB0 = rnf8 + (size_t)(colB0 + warp * 16 + r4) * 1024 + csw * 16;

    f32x4 acc[4][2];
#pragma unroll
    for (int a = 0; a < 4; ++a)
#pragma unroll
        for (int b = 0; b < 2; ++b) acc[a][b] = (f32x4){0.f, 0.f, 0.f, 0.f};

    // frag LDS offset: global 16B-chunk g of row r lives at slot g^((r>>1)&3)
    int fsw = (g ^ ((m_ >> 1) & 3)) * 16;

    // prologue: stage kt=0 into buffer 0
    GLD16(gA0, &As[0][(warp * 16) * 64]);
    GLD16(gB0, &Bs[0][(warp * 16) * 64]);

    for (int kt = 0; kt < 16; ++kt) {
        int cur = kt & 1;
        // barrier's implicit vmcnt(0)/lgkmcnt(0): stage(kt) landed (issued a
        // full compute phase ago) and all reads of buf[cur^1] are complete.
        __syncthreads();
        // ds_read frags FIRST, then issue stage(kt+1), then the MFMA cluster.
        f32x4 aq[4], bq[2];
#pragma unroll
        for (int ti = 0; ti < 4; ++ti) {
            int rowLoc = wr * 64 + ti * 16 + m_;
            aq[ti] = *(const f32x4*)&As[cur][rowLoc * 64 + fsw];
        }
#pragma unroll
        for (int tj = 0; tj < 2; ++tj) {
            int colLoc = wc * 32 + tj * 16 + m_;
            bq[tj] = *(const f32x4*)&Bs[cur][colLoc * 64 + fsw];
        }
        if (kt < 15) {
            int nxt = cur ^ 1;
            GLD16(gA0 + (kt + 1) * 64, &As[nxt][(warp * 16) * 64]);
            GLD16(gB0 + (kt + 1) * 64, &Bs[nxt][(warp * 16) * 64]);
        }
#pragma unroll
        for (int s = 0; s < 2; ++s)
#pragma unroll
            for (int ti = 0; ti < 4; ++ti)
#pragma unroll
                for (int tj = 0; tj < 2; ++tj) {
                    i64 a = ((const i64*)&aq[ti])[s];
                    i64 b = ((const i64*)&bq[tj])[s];
                    acc[ti][tj] = __builtin_amdgcn_mfma_f32_16x16x32_fp8_fp8(
                        a, b, acc[ti][tj], 0, 0, 0);
                }
    }

    // epilogue: C layout col=lane&15, row=(lane>>4)*4+reg
    bool isDiag = (bi == bj);
    int cl = m_;
    float colE[2] = {0.f, 0.f}, colP[2] = {0.f, 0.f};
#pragma unroll
    for (int ti = 0; ti < 4; ++ti) {
        int rowLoc = wr * 64 + ti * 16 + g * 4;
        float rE[4] = {0.f, 0.f, 0.f, 0.f}, rP[4] = {0.f, 0.f, 0.f, 0.f};
        int lr[4];
#pragma unroll
        for (int r = 0; r < 4; ++r) lr[r] = lblA[rowLoc + r];
#pragma unroll
        for (int tj = 0; tj < 2; ++tj) {
            int colLoc = wc * 32 + tj * 16 + cl;
            int gCol = colB0 + colLoc;
            int lc = lblB[colLoc];
            f32x4 a = acc[ti][tj];
#pragma unroll
            for (int r = 0; r < 4; ++r) {
                int gRow = rowA0 + rowLoc + r;
                float z = Z_SCALE * a[r];
                float e = __expf(z);
                bool offd = (gRow != gCol);
                if (!offd) e = 0.f;
                rE[r] += e;
                colE[tj] += e;
                if (offd && (lr[r] == lc)) { rP[r] += z; colP[tj] += z; }
            }
        }
#pragma unroll
        for (int r = 0; r < 4; ++r) {
            float v = rE[r], p = rP[r];
#pragma unroll
            for (int msk = 1; msk < 16; msk <<= 1) {
                v += __shfl_xor(v, msk, 64);
                p += __shfl_xor(p, msk, 64);
            }
            if (cl == 0) {
                int gRow = rowA0 + rowLoc + r;
                atomicAdd(&denom[gRow], v);
                atomicAdd(&posS[gRow], p);
            }
        }
    }
    if (!isDiag) {
#pragma unroll
        for (int tj = 0; tj < 2; ++tj) {
            float v = colE[tj], p = colP[tj];
            v += __shfl_xor(v, 16, 64); p += __shfl_xor(p, 16, 64);
            v += __shfl_xor(v, 32, 64); p += __shfl_xor(p, 32, 64);
            if (g == 0) {
                int gCol = colB0 + wc * 32 + tj * 16 + cl;
                atomicAdd(&denom[gCol], v);
                atomicAdd(&posS[gCol], p);
            }
        }
    }
}

// ---------------- D3: finalize (8 row-blocks + 1 G-block), done-counter -----
__global__ __launch_bounds__(256) void scl_finalize(const float* __restrict__ denom,
                                                    const float* __restrict__ posS,
                                                    const float* __restrict__ W,
                                                    const float* __restrict__ G,
                                                    const int* __restrict__ pwp,
                                                    double* __restrict__ oacc,
                                                    int* __restrict__ done,
                                                    float* __restrict__ out) {
    int t = threadIdx.x;
    __shared__ double wsum[4];
    double contrib = 0.0;

    if (blockIdx.x < 8) {
        int i0 = blockIdx.x * 512 + t;
        float t0 = __logf(denom[i0]) * W[i0] - posS[i0];
        float t1 = __logf(denom[i0 + 256]) * W[i0 + 256] - posS[i0 + 256];
        double td = (double)t0 + (double)t1;
#pragma unroll
        for (int m = 1; m < 64; m <<= 1) td += __shfl_xor(td, m, 64);
        if ((t & 63) == 0) wsum[t >> 6] = td;
        __syncthreads();
        contrib = wsum[0] + wsum[1] + wsum[2] + wsum[3];
    } else {
        int bits = *pwp;
        float pw = (bits >= -(1 << 22) && bits <= (1 << 22)) ? (float)bits
                                                             : __int_as_float(bits);
        const f32x4* G4 = (const f32x4*)G;
        float gs = 0.f;
#pragma unroll
        for (int q = 0; q < 32; ++q) {
            f32x4 v = G4[q * 256 + t];
            gs += v[0] * v[0] + v[1] * v[1] + v[2] * v[2] + v[3] * v[3];
        }
        double gd = (double)gs;
#pragma unroll
        for (int m = 1; m < 64; m <<= 1) gd += __shfl_xor(gd, m, 64);
        if ((t & 63) == 0) wsum[t >> 6] = gd;
        __syncthreads();
        contrib = -(double)(pw * INV_T) * (wsum[0] + wsum[1] + wsum[2] + wsum[3]);
    }

    if (t == 0) {
        atomicAdd(oacc, contrib);
        __threadfence();
        int old = atomicAdd(done, 1);
        if (old == 8) {  // last of 9 blocks
            double tot = atomicAdd(oacc, 0.0);  // coherent read
            out[0] = (float)(tot * (1.0 / 4096.0));
        }
    }
}

// ---------------------------------------------------------------------------
extern "C" void kernel_launch(void* const* d_in, const int* in_sizes, int n_in,
                              void* d_out, int out_size, void* d_ws, size_t ws_size,
                              hipStream_t stream) {
    const float* rep = (const float*)d_in[0];
    const float* sl = (const float*)d_in[1];
    const int* labels = (const int*)d_in[2];
    const int* pwp = (const int*)d_in[3];

    char* ws = (char*)d_ws;
    uint8_t* rnf8 = (uint8_t*)(ws + OFF_RNF8);
    float* denom = (float*)(ws + OFF_DENOM);
    float* posS = (float*)(ws + OFF_POSS);
    float* G = (float*)(ws + OFF_G);
    double* oacc = (double*)(ws + OFF_OACC);
    int* done = (int*)(ws + OFF_DONE);
    float* cs_part = (float*)(ws + OFF_CSP);
    int* cc_part = (int*)(ws + OFF_CCP);
    float* W = (float*)(ws + OFF_W);

    scl_stage1<<<4169, 256, 0, stream>>>(rep, sl, labels, (uint32_t*)rnf8,
                                         cs_part, cc_part, ws + OFF_DENOM);
    scl_main<<<N_ALL, 512, 0, stream>>>(rnf8, sl, labels, cs_part, cc_part, pwp,
                                        denom, posS, G, W);
    scl_finalize<<<9, 256, 0, stream>>>(denom, posS, W, G, pwp, oacc, done,
                                        (float*)d_out);
}

// Round 5
// 115.934 us; speedup vs baseline: 1.1623x; 1.1623x over previous
//
#include <hip/hip_runtime.h>
#include <hip/hip_bf16.h>
#include <stdint.h>

// ---------------------------------------------------------------------------
// SupervisedContrastiveLoss, B=4096, D=1024, C=32, T=0.1, eps=1e-8
// out = (1/B) * [ sum_i (log(denom_i)*W_i - posS_i) - pw*INV_T*||G||_F^2 ]
// R9: 3 dispatches. R5 geometry (128x128 upper-tri, 4 waves) but the K-loop
//     uses TRIPLE-buffered LDS + raw s_barrier + counted s_waitcnt vmcnt(4)
//     (never 0 in-loop): stage(t+1) stays in flight across the barrier,
//     removing the implicit vmcnt(0) drain of __syncthreads (m97 stall).
//   D1: normalize->fp8(x16) + prep partials + zero
//   D2: 528 gemm tiles (XCD-swizzled 528=8*66) + 512 G + 16 W
//   D3: finalize (9 blocks, done-counter writes out)
// ---------------------------------------------------------------------------

typedef float f32x4 __attribute__((ext_vector_type(4)));
typedef long i64;

#define INV_T 10.0f
#define Z_SCALE (INV_T / 256.0f)   // both fp8 operands carry x16

#define GLD16(gp, lp)                                                          \
    __builtin_amdgcn_global_load_lds(                                          \
        (const __attribute__((address_space(1))) uint32_t*)(gp),               \
        (__attribute__((address_space(3))) uint32_t*)(lp), 16, 0, 0)

// workspace layout (bytes)
#define OFF_RNF8  0                         // 4096*1024 = 4194304
#define OFF_DENOM 4194304                   // 4096*4
#define OFF_POSS  (OFF_DENOM + 16384)
#define OFF_G     (OFF_POSS + 16384)        // 1024*32*4 = 131072
#define OFF_OACC  (OFF_G + 131072)          // double
#define OFF_DONE  (OFF_OACC + 16)           // int
#define ZERO_SPAN 167936                    // 41*4096 >= 163904 (zeroed region)
#define OFF_CSP   (OFF_DENOM + ZERO_SPAN)   // 32*32*4 colsum partials
#define OFF_CCP   (OFF_CSP + 4096)          // 32*32*4 histogram partials
#define OFF_W     (OFF_CCP + 4096)          // 4096*4

#define N_GEMM 528
#define N_G    512
#define N_W    16
#define N_ALL  (N_GEMM + N_G + N_W)         // 1056

// ---------------- D1: normalize -> fp8(x16) | prep partials | zero ----------
__global__ __launch_bounds__(256) void scl_stage1(const float* __restrict__ rep,
                                                  const float* __restrict__ sl,
                                                  const int* __restrict__ labels,
                                                  uint32_t* __restrict__ rnf8,
                                                  float* __restrict__ cs_part,
                                                  int* __restrict__ cc_part,
                                                  char* __restrict__ zbase) {
    int b = blockIdx.x;
    int t = threadIdx.x;
    if (b < 4096) {
        int row = b;
        const float4* src = reinterpret_cast<const float4*>(rep + (size_t)row * 1024);
        float4 v = src[t];
        float s = v.x * v.x + v.y * v.y + v.z * v.z + v.w * v.w;
#pragma unroll
        for (int m = 1; m < 64; m <<= 1) s += __shfl_xor(s, m, 64);
        __shared__ float red[4];
        if ((t & 63) == 0) red[t >> 6] = s;
        __syncthreads();
        s = red[0] + red[1] + red[2] + red[3];
        float nf = 16.0f / fmaxf(sqrtf(s), 1e-8f);   // x16 into fp8 normal range
        int p = 0;
        p = __builtin_amdgcn_cvt_pk_fp8_f32(v.x * nf, v.y * nf, p, false);
        p = __builtin_amdgcn_cvt_pk_fp8_f32(v.z * nf, v.w * nf, p, true);
        rnf8[row * 256 + t] = (uint32_t)p;
    } else if (b < 4128) {
        // prep partials: colsum of soft_labels + class histogram (128 rows/slab)
        __shared__ float part[8][32];
        __shared__ int bins[32];
        int bb = b - 4096;
        if (t < 32) bins[t] = 0;
        __syncthreads();
        if (t < 128) atomicAdd(&bins[labels[bb * 128 + t]], 1);
        int c = t & 31, rg = t >> 5;
        float s = 0.f;
#pragma unroll 4
        for (int k = 0; k < 16; ++k) {
            int i = bb * 128 + rg * 16 + k;
            s += sl[i * 32 + c];
        }
        part[rg][c] = s;
        __syncthreads();
        if (t < 32) {
            float tot = 0.f;
#pragma unroll
            for (int g = 0; g < 8; ++g) tot += part[g][t];
            cs_part[bb * 32 + t] = tot;
            cc_part[bb * 32 + t] = bins[t];
        }
    } else {
        // zero blocks: denom/posS/G/oacc/done (consumed in D2/D3)
        int zb = b - 4128;
        *(uint4*)(zbase + (size_t)zb * 4096 + t * 16) = (uint4){0, 0, 0, 0};
    }
}

// ---------------- D2: fused gemm + G + W ------------------------------------
__global__ __launch_bounds__(256) void scl_main(const uint8_t* __restrict__ rnf8,
                                                const float* __restrict__ sl,
                                                const int* __restrict__ labels,
                                                const float* __restrict__ cs_part,
                                                const int* __restrict__ cc_part,
                                                const int* __restrict__ pwp,
                                                float* __restrict__ denom,
                                                float* __restrict__ posS,
                                                float* __restrict__ G,
                                                float* __restrict__ W) {
    int tid = threadIdx.x;
    int bIdx = blockIdx.x;

    if (bIdx >= N_GEMM) {
        if (bIdx < N_GEMM + N_G) {
            // ---- G = rn^T @ SL : 16 d-blocks x 32 k-splits ----
            int idx = bIdx - N_GEMM;
            int dblk = idx & 15, ks = idx >> 4;
            int dq = tid >> 5, c = tid & 31;
            int d0 = dblk * 64 + dq * 8;
            float acc[8];
#pragma unroll
            for (int j = 0; j < 8; ++j) acc[j] = 0.f;
            int i0 = ks * 128;
#pragma unroll 4
            for (int k = 0; k < 128; ++k) {
                int i = i0 + k;
                uint2 rv = *(const uint2*)&rnf8[(size_t)i * 1024 + d0];
                float sv = sl[i * 32 + c];
                acc[0] += __builtin_amdgcn_cvt_f32_fp8((int)rv.x, 0) * sv;
                acc[1] += __builtin_amdgcn_cvt_f32_fp8((int)rv.x, 1) * sv;
                acc[2] += __builtin_amdgcn_cvt_f32_fp8((int)rv.x, 2) * sv;
                acc[3] += __builtin_amdgcn_cvt_f32_fp8((int)rv.x, 3) * sv;
                acc[4] += __builtin_amdgcn_cvt_f32_fp8((int)rv.y, 0) * sv;
                acc[5] += __builtin_amdgcn_cvt_f32_fp8((int)rv.y, 1) * sv;
                acc[6] += __builtin_amdgcn_cvt_f32_fp8((int)rv.y, 2) * sv;
                acc[7] += __builtin_amdgcn_cvt_f32_fp8((int)rv.y, 3) * sv;
            }
#pragma unroll
            for (int j = 0; j < 8; ++j)
                atomicAdd(&G[(d0 + j) * 32 + c], acc[j] * 0.0625f);  // undo x16
        } else {
            // ---- W[i] = (ccnt[l_i]-1) + pw*(sl_i . csum) : 16 blocks x 256 rows
            __shared__ __align__(16) float css[32];
            __shared__ int ccs[32];
            if (tid < 32) {
                float s = 0.f; int n = 0;
#pragma unroll
                for (int b = 0; b < 32; ++b) { s += cs_part[b * 32 + tid]; n += cc_part[b * 32 + tid]; }
                css[tid] = s; ccs[tid] = n;
            }
            __syncthreads();
            int bits = *pwp;
            float pw = (bits >= -(1 << 22) && bits <= (1 << 22)) ? (float)bits
                                                                 : __int_as_float(bits);
            int i = (bIdx - (N_GEMM + N_G)) * 256 + tid;
            const f32x4* sl4 = (const f32x4*)sl;
            const f32x4* cs4 = (const f32x4*)css;
            float dW = 0.f;
#pragma unroll
            for (int q = 0; q < 8; ++q) {
                f32x4 s = sl4[i * 8 + q];
                f32x4 c = cs4[q];
                dW += s[0] * c[0] + s[1] * c[1] + s[2] * c[2] + s[3] * c[3];
            }
            W[i] = (float)(ccs[labels[i]] - 1) + pw * dW;
        }
        return;
    }

    // ---- main fp8 GEMM tile (128x128, 4 waves, triple-buffered) ----
    __shared__ __align__(16) uint8_t As[3][128 * 64];
    __shared__ __align__(16) uint8_t Bs[3][128 * 64];
    __shared__ int lblA[128], lblB[128];

    // XCD-bijective swizzle: 528 = 8*66; XCD x gets 66 contiguous tiles.
    int L = (bIdx & 7) * 66 + (bIdx >> 3);
    int bi = 0, rem = L;
    while (rem >= 32 - bi) { rem -= 32 - bi; ++bi; }
    int bj = bi + rem;
    int rowA0 = bi * 128, colB0 = bj * 128;

    if (tid < 128) {
        lblA[tid] = labels[rowA0 + tid];
        lblB[tid] = labels[colB0 + tid];
    }

    int lane = tid & 63, warp = tid >> 6;
    int wr = warp >> 1, wc = warp & 1;
    int m_ = lane & 15, g = lane >> 4;

    // staging: lane l -> row l>>2, LDS slot l&3; fetch global chunk (l&3)^((l>>3)&3)
    int r4 = lane >> 2;
    int csw = (lane & 3) ^ ((lane >> 3) & 3);
    const uint8_t* gA0 = rnf8 + (size_t)(rowA0 + warp * 32 + r4) * 1024 + csw * 16;
    const uint8_t* gB0 = rnf8 + (size_t)(colB0 + warp * 32 + r4) * 1024 + csw * 16;

    f32x4 acc[4][4];
#pragma unroll
    for (int a = 0; a < 4; ++a)
#pragma unroll
        for (int b = 0; b < 4; ++b) acc[a][b] = (f32x4){0.f, 0.f, 0.f, 0.f};

    // frag LDS offset: global 16B-chunk g of row r lives at slot g^((r>>1)&3)
    int fsw = (g ^ ((m_ >> 1) & 3)) * 16;

    // prologue: stage kt=0 -> buf0, kt=1 -> buf1 (8 GLD16 in flight)
    GLD16(gA0,       &As[0][(warp * 32) * 64]);
    GLD16(gA0 + 16384, &As[0][(warp * 32 + 16) * 64]);
    GLD16(gB0,       &Bs[0][(warp * 32) * 64]);
    GLD16(gB0 + 16384, &Bs[0][(warp * 32 + 16) * 64]);
    GLD16(gA0 + 64,        &As[1][(warp * 32) * 64]);
    GLD16(gA0 + 64 + 16384, &As[1][(warp * 32 + 16) * 64]);
    GLD16(gB0 + 64,        &Bs[1][(warp * 32) * 64]);
    GLD16(gB0 + 64 + 16384, &Bs[1][(warp * 32 + 16) * 64]);

    // publish label ds_writes at the first barrier
    asm volatile("s_waitcnt lgkmcnt(0)" ::: "memory");

    // K-loop: counted vmcnt(4) — stage(kt) drained, stage(kt+1) in flight.
    for (int kt = 0; kt < 15; ++kt) {
        int cur = kt % 3;
        asm volatile("s_waitcnt vmcnt(4)" ::: "memory");
        __builtin_amdgcn_s_barrier();
        __builtin_amdgcn_sched_barrier(0);
        f32x4 aq[4], bq[4];
#pragma unroll
        for (int ti = 0; ti < 4; ++ti) {
            int rowLoc = wr * 64 + ti * 16 + m_;
            aq[ti] = *(const f32x4*)&As[cur][rowLoc * 64 + fsw];
        }
#pragma unroll
        for (int tj = 0; tj < 4; ++tj) {
            int colLoc = wc * 64 + tj * 16 + m_;
            bq[tj] = *(const f32x4*)&Bs[cur][colLoc * 64 + fsw];
        }
        if (kt < 14) {
            int nxt = (kt + 2) % 3;
            GLD16(gA0 + (kt + 2) * 64,         &As[nxt][(warp * 32) * 64]);
            GLD16(gA0 + (kt + 2) * 64 + 16384, &As[nxt][(warp * 32 + 16) * 64]);
            GLD16(gB0 + (kt + 2) * 64,         &Bs[nxt][(warp * 32) * 64]);
            GLD16(gB0 + (kt + 2) * 64 + 16384, &Bs[nxt][(warp * 32 + 16) * 64]);
        }
#pragma unroll
        for (int s = 0; s < 2; ++s)
#pragma unroll
            for (int ti = 0; ti < 4; ++ti)
#pragma unroll
                for (int tj = 0; tj < 4; ++tj) {
                    i64 a = ((const i64*)&aq[ti])[s];
                    i64 b = ((const i64*)&bq[tj])[s];
                    acc[ti][tj] = __builtin_amdgcn_mfma_f32_16x16x32_fp8_fp8(
                        a, b, acc[ti][tj], 0, 0, 0);
                }
    }
    {   // peeled last step (kt=15): only stage(15) outstanding -> vmcnt(0)
        int cur = 15 % 3;
        asm volatile("s_waitcnt vmcnt(0)" ::: "memory");
        __builtin_amdgcn_s_barrier();
        __builtin_amdgcn_sched_barrier(0);
        f32x4 aq[4], bq[4];
#pragma unroll
        for (int ti = 0; ti < 4; ++ti) {
            int rowLoc = wr * 64 + ti * 16 + m_;
            aq[ti] = *(const f32x4*)&As[cur][rowLoc * 64 + fsw];
        }
#pragma unroll
        for (int tj = 0; tj < 4; ++tj) {
            int colLoc = wc * 64 + tj * 16 + m_;
            bq[tj] = *(const f32x4*)&Bs[cur][colLoc * 64 + fsw];
        }
#pragma unroll
        for (int s = 0; s < 2; ++s)
#pragma unroll
            for (int ti = 0; ti < 4; ++ti)
#pragma unroll
                for (int tj = 0; tj < 4; ++tj) {
                    i64 a = ((const i64*)&aq[ti])[s];
                    i64 b = ((const i64*)&bq[tj])[s];
                    acc[ti][tj] = __builtin_amdgcn_mfma_f32_16x16x32_fp8_fp8(
                        a, b, acc[ti][tj], 0, 0, 0);
                }
    }

    // epilogue: C layout col=lane&15, row=(lane>>4)*4+reg
    bool isDiag = (bi == bj);
    int cl = m_;
    float colE[4] = {0.f, 0.f, 0.f, 0.f}, colP[4] = {0.f, 0.f, 0.f, 0.f};
#pragma unroll
    for (int ti = 0; ti < 4; ++ti) {
        int rowLoc = wr * 64 + ti * 16 + g * 4;
        float rE[4] = {0.f, 0.f, 0.f, 0.f}, rP[4] = {0.f, 0.f, 0.f, 0.f};
        int lr[4];
#pragma unroll
        for (int r = 0; r < 4; ++r) lr[r] = lblA[rowLoc + r];
#pragma unroll
        for (int tj = 0; tj < 4; ++tj) {
            int colLoc = wc * 64 + tj * 16 + cl;
            int gCol = colB0 + colLoc;
            int lc = lblB[colLoc];
            f32x4 a = acc[ti][tj];
#pragma unroll
            for (int r = 0; r < 4; ++r) {
                int gRow = rowA0 + rowLoc + r;
                float z = Z_SCALE * a[r];
                float e = __expf(z);
                bool offd = (gRow != gCol);
                if (!offd) e = 0.f;
                rE[r] += e;
                colE[tj] += e;
                if (offd && (lr[r] == lc)) { rP[r] += z; colP[tj] += z; }
            }
        }
#pragma unroll
        for (int r = 0; r < 4; ++r) {
            float v = rE[r], p = rP[r];
#pragma unroll
            for (int msk = 1; msk < 16; msk <<= 1) {
                v += __shfl_xor(v, msk, 64);
                p += __shfl_xor(p, msk, 64);
            }
            if (cl == 0) {
                int gRow = rowA0 + rowLoc + r;
                atomicAdd(&denom[gRow], v);
                atomicAdd(&posS[gRow], p);
            }
        }
    }
    if (!isDiag) {
#pragma unroll
        for (int tj = 0; tj < 4; ++tj) {
            float v = colE[tj], p = colP[tj];
            v += __shfl_xor(v, 16, 64); p += __shfl_xor(p, 16, 64);
            v += __shfl_xor(v, 32, 64); p += __shfl_xor(p, 32, 64);
            if (g == 0) {
                int gCol = colB0 + wc * 64 + tj * 16 + cl;
                atomicAdd(&denom[gCol], v);
                atomicAdd(&posS[gCol], p);
            }
        }
    }
}

// ---------------- D3: finalize (8 row-blocks + 1 G-block), done-counter -----
__global__ __launch_bounds__(256) void scl_finalize(const float* __restrict__ denom,
                                                    const float* __restrict__ posS,
                                                    const float* __restrict__ W,
                                                    const float* __restrict__ G,
                                                    const int* __restrict__ pwp,
                                                    double* __restrict__ oacc,
                                                    int* __restrict__ done,
                                                    float* __restrict__ out) {
    int t = threadIdx.x;
    __shared__ double wsum[4];
    double contrib = 0.0;

    if (blockIdx.x < 8) {
        int i0 = blockIdx.x * 512 + t;
        float t0 = __logf(denom[i0]) * W[i0] - posS[i0];
        float t1 = __logf(denom[i0 + 256]) * W[i0 + 256] - posS[i0 + 256];
        double td = (double)t0 + (double)t1;
#pragma unroll
        for (int m = 1; m < 64; m <<= 1) td += __shfl_xor(td, m, 64);
        if ((t & 63) == 0) wsum[t >> 6] = td;
        __syncthreads();
        contrib = wsum[0] + wsum[1] + wsum[2] + wsum[3];
    } else {
        int bits = *pwp;
        float pw = (bits >= -(1 << 22) && bits <= (1 << 22)) ? (float)bits
                                                             : __int_as_float(bits);
        const f32x4* G4 = (const f32x4*)G;
        float gs = 0.f;
#pragma unroll
        for (int q = 0; q < 32; ++q) {
            f32x4 v = G4[q * 256 + t];
            gs += v[0] * v[0] + v[1] * v[1] + v[2] * v[2] + v[3] * v[3];
        }
        double gd = (double)gs;
#pragma unroll
        for (int m = 1; m < 64; m <<= 1) gd += __shfl_xor(gd, m, 64);
        if ((t & 63) == 0) wsum[t >> 6] = gd;
        __syncthreads();
        contrib = -(double)(pw * INV_T) * (wsum[0] + wsum[1] + wsum[2] + wsum[3]);
    }

    if (t == 0) {
        atomicAdd(oacc, contrib);
        __threadfence();
        int old = atomicAdd(done, 1);
        if (old == 8) {  // last of 9 blocks
            double tot = atomicAdd(oacc, 0.0);  // coherent read
            out[0] = (float)(tot * (1.0 / 4096.0));
        }
    }
}

// ---------------------------------------------------------------------------
extern "C" void kernel_launch(void* const* d_in, const int* in_sizes, int n_in,
                              void* d_out, int out_size, void* d_ws, size_t ws_size,
                              hipStream_t stream) {
    const float* rep = (const float*)d_in[0];
    const float* sl = (const float*)d_in[1];
    const int* labels = (const int*)d_in[2];
    const int* pwp = (const int*)d_in[3];

    char* ws = (char*)d_ws;
    uint8_t* rnf8 = (uint8_t*)(ws + OFF_RNF8);
    float* denom = (float*)(ws + OFF_DENOM);
    float* posS = (float*)(ws + OFF_POSS);
    float* G = (float*)(ws + OFF_G);
    double* oacc = (double*)(ws + OFF_OACC);
    int* done = (int*)(ws + OFF_DONE);
    float* cs_part = (float*)(ws + OFF_CSP);
    int* cc_part = (int*)(ws + OFF_CCP);
    float* W = (float*)(ws + OFF_W);

    scl_stage1<<<4169, 256, 0, stream>>>(rep, sl, labels, (uint32_t*)rnf8,
                                         cs_part, cc_part, ws + OFF_DENOM);
    scl_main<<<N_ALL, 256, 0, stream>>>(rnf8, sl, labels, cs_part, cc_part, pwp,
                                        denom, posS, G, W);
    scl_finalize<<<9, 256, 0, stream>>>(denom, posS, W, G, pwp, oacc, done,
                                        (float*)d_out);
}

// Round 6
// 114.405 us; speedup vs baseline: 1.1778x; 1.0134x over previous
//
#include <hip/hip_runtime.h>
#include <hip/hip_bf16.h>
#include <stdint.h>

// ---------------------------------------------------------------------------
// SupervisedContrastiveLoss, B=4096, D=1024, C=32, T=0.1, eps=1e-8
// out = (1/B) * [ sum_i (log(denom_i)*W_i - posS_i) - pw*INV_T*||G||_F^2 ]
// R10: 4 dispatches — ATTRIBUTION SPLIT of the fused D2.
//   D1: normalize->fp8(x16) + prep partials + zero
//   D2a: scl_gw  — 512 G blocks (LDS-staged slabs, pure LDS+VALU inner loop)
//                 + 16 W blocks.  24 KB LDS -> high occupancy.
//   D2b: scl_gemm — 528 gemm tiles, R9 K-loop verbatim (triple-buffer,
//                 counted vmcnt(4), raw barriers, XCD swizzle 528=8*66)
//   D3: finalize (9 blocks, done-counter writes out)
// ---------------------------------------------------------------------------

typedef float f32x4 __attribute__((ext_vector_type(4)));
typedef long i64;

#define INV_T 10.0f
#define Z_SCALE (INV_T / 256.0f)   // both fp8 operands carry x16

#define GLD16(gp, lp)                                                          \
    __builtin_amdgcn_global_load_lds(                                          \
        (const __attribute__((address_space(1))) uint32_t*)(gp),               \
        (__attribute__((address_space(3))) uint32_t*)(lp), 16, 0, 0)

// workspace layout (bytes)
#define OFF_RNF8  0                         // 4096*1024 = 4194304
#define OFF_DENOM 4194304                   // 4096*4
#define OFF_POSS  (OFF_DENOM + 16384)
#define OFF_G     (OFF_POSS + 16384)        // 1024*32*4 = 131072
#define OFF_OACC  (OFF_G + 131072)          // double
#define OFF_DONE  (OFF_OACC + 16)           // int
#define ZERO_SPAN 167936                    // 41*4096 >= 163904 (zeroed region)
#define OFF_CSP   (OFF_DENOM + ZERO_SPAN)   // 32*32*4 colsum partials
#define OFF_CCP   (OFF_CSP + 4096)          // 32*32*4 histogram partials
#define OFF_W     (OFF_CCP + 4096)          // 4096*4

#define N_GEMM 528
#define N_G    512
#define N_W    16

// ---------------- D1: normalize -> fp8(x16) | prep partials | zero ----------
__global__ __launch_bounds__(256) void scl_stage1(const float* __restrict__ rep,
                                                  const float* __restrict__ sl,
                                                  const int* __restrict__ labels,
                                                  uint32_t* __restrict__ rnf8,
                                                  float* __restrict__ cs_part,
                                                  int* __restrict__ cc_part,
                                                  char* __restrict__ zbase) {
    int b = blockIdx.x;
    int t = threadIdx.x;
    if (b < 4096) {
        int row = b;
        const float4* src = reinterpret_cast<const float4*>(rep + (size_t)row * 1024);
        float4 v = src[t];
        float s = v.x * v.x + v.y * v.y + v.z * v.z + v.w * v.w;
#pragma unroll
        for (int m = 1; m < 64; m <<= 1) s += __shfl_xor(s, m, 64);
        __shared__ float red[4];
        if ((t & 63) == 0) red[t >> 6] = s;
        __syncthreads();
        s = red[0] + red[1] + red[2] + red[3];
        float nf = 16.0f / fmaxf(sqrtf(s), 1e-8f);   // x16 into fp8 normal range
        int p = 0;
        p = __builtin_amdgcn_cvt_pk_fp8_f32(v.x * nf, v.y * nf, p, false);
        p = __builtin_amdgcn_cvt_pk_fp8_f32(v.z * nf, v.w * nf, p, true);
        rnf8[row * 256 + t] = (uint32_t)p;
    } else if (b < 4128) {
        // prep partials: colsum of soft_labels + class histogram (128 rows/slab)
        __shared__ float part[8][32];
        __shared__ int bins[32];
        int bb = b - 4096;
        if (t < 32) bins[t] = 0;
        __syncthreads();
        if (t < 128) atomicAdd(&bins[labels[bb * 128 + t]], 1);
        int c = t & 31, rg = t >> 5;
        float s = 0.f;
#pragma unroll 4
        for (int k = 0; k < 16; ++k) {
            int i = bb * 128 + rg * 16 + k;
            s += sl[i * 32 + c];
        }
        part[rg][c] = s;
        __syncthreads();
        if (t < 32) {
            float tot = 0.f;
#pragma unroll
            for (int g = 0; g < 8; ++g) tot += part[g][t];
            cs_part[bb * 32 + t] = tot;
            cc_part[bb * 32 + t] = bins[t];
        }
    } else {
        // zero blocks: denom/posS/G/oacc/done (consumed in D2/D3)
        int zb = b - 4128;
        *(uint4*)(zbase + (size_t)zb * 4096 + t * 16) = (uint4){0, 0, 0, 0};
    }
}

// ---------------- D2a: G (LDS-staged) + W -----------------------------------
__global__ __launch_bounds__(256) void scl_gw(const uint8_t* __restrict__ rnf8,
                                              const float* __restrict__ sl,
                                              const int* __restrict__ labels,
                                              const float* __restrict__ cs_part,
                                              const int* __restrict__ cc_part,
                                              const int* __restrict__ pwp,
                                              float* __restrict__ G,
                                              float* __restrict__ W) {
    int tid = threadIdx.x;
    int bIdx = blockIdx.x;

    if (bIdx < N_G) {
        // ---- G = rn^T @ SL : 16 d-blocks x 32 k-splits, slabs in LDS ----
        __shared__ __align__(16) uint8_t rns[128 * 64];  // 8 KB
        __shared__ __align__(16) float sls[128 * 32];    // 16 KB
        int dblk = bIdx & 15, ks = bIdx >> 4;
        int i0 = ks * 128;
        // stage rn slab: 128 rows x 64 B (dims dblk*64..+64)
#pragma unroll
        for (int p = 0; p < 2; ++p) {
            int off = p * 4096 + tid * 16;        // byte offset in slab
            int row = off >> 6, col = off & 63;
            *(uint4*)&rns[off] =
                *(const uint4*)&rnf8[(size_t)(i0 + row) * 1024 + dblk * 64 + col];
        }
        // stage sl slab: 128 x 32 floats, contiguous
#pragma unroll
        for (int p = 0; p < 4; ++p) {
            int off = p * 1024 + tid * 4;         // float index
            *(float4*)&sls[off] = *(const float4*)&sl[(size_t)i0 * 32 + off];
        }
        __syncthreads();
        int dq = tid >> 5, c = tid & 31;
        int d0 = dblk * 64 + dq * 8;
        float acc[8];
#pragma unroll
        for (int j = 0; j < 8; ++j) acc[j] = 0.f;
#pragma unroll 4
        for (int k = 0; k < 128; ++k) {
            uint2 rv = *(const uint2*)&rns[k * 64 + dq * 8];  // ds broadcast
            float sv = sls[k * 32 + c];                        // ds broadcast
            acc[0] += __builtin_amdgcn_cvt_f32_fp8((int)rv.x, 0) * sv;
            acc[1] += __builtin_amdgcn_cvt_f32_fp8((int)rv.x, 1) * sv;
            acc[2] += __builtin_amdgcn_cvt_f32_fp8((int)rv.x, 2) * sv;
            acc[3] += __builtin_amdgcn_cvt_f32_fp8((int)rv.x, 3) * sv;
            acc[4] += __builtin_amdgcn_cvt_f32_fp8((int)rv.y, 0) * sv;
            acc[5] += __builtin_amdgcn_cvt_f32_fp8((int)rv.y, 1) * sv;
            acc[6] += __builtin_amdgcn_cvt_f32_fp8((int)rv.y, 2) * sv;
            acc[7] += __builtin_amdgcn_cvt_f32_fp8((int)rv.y, 3) * sv;
        }
#pragma unroll
        for (int j = 0; j < 8; ++j)
            atomicAdd(&G[(d0 + j) * 32 + c], acc[j] * 0.0625f);  // undo x16
    } else {
        // ---- W[i] = (ccnt[l_i]-1) + pw*(sl_i . csum) : 16 blocks x 256 rows
        __shared__ __align__(16) float css[32];
        __shared__ int ccs[32];
        if (tid < 32) {
            float s = 0.f; int n = 0;
#pragma unroll
            for (int b = 0; b < 32; ++b) { s += cs_part[b * 32 + tid]; n += cc_part[b * 32 + tid]; }
            css[tid] = s; ccs[tid] = n;
        }
        __syncthreads();
        int bits = *pwp;
        float pw = (bits >= -(1 << 22) && bits <= (1 << 22)) ? (float)bits
                                                             : __int_as_float(bits);
        int i = (bIdx - N_G) * 256 + tid;
        const f32x4* sl4 = (const f32x4*)sl;
        const f32x4* cs4 = (const f32x4*)css;
        float dW = 0.f;
#pragma unroll
        for (int q = 0; q < 8; ++q) {
            f32x4 s = sl4[i * 8 + q];
            f32x4 c = cs4[q];
            dW += s[0] * c[0] + s[1] * c[1] + s[2] * c[2] + s[3] * c[3];
        }
        W[i] = (float)(ccs[labels[i]] - 1) + pw * dW;
    }
}

// ---------------- D2b: GEMM tiles (R9 K-loop verbatim) ----------------------
__global__ __launch_bounds__(256) void scl_gemm(const uint8_t* __restrict__ rnf8,
                                                const int* __restrict__ labels,
                                                float* __restrict__ denom,
                                                float* __restrict__ posS) {
    int tid = threadIdx.x;
    int bIdx = blockIdx.x;

    // ---- main fp8 GEMM tile (128x128, 4 waves, triple-buffered) ----
    __shared__ __align__(16) uint8_t As[3][128 * 64];
    __shared__ __align__(16) uint8_t Bs[3][128 * 64];
    __shared__ int lblA[128], lblB[128];

    // XCD-bijective swizzle: 528 = 8*66; XCD x gets 66 contiguous tiles.
    int L = (bIdx & 7) * 66 + (bIdx >> 3);
    int bi = 0, rem = L;
    while (rem >= 32 - bi) { rem -= 32 - bi; ++bi; }
    int bj = bi + rem;
    int rowA0 = bi * 128, colB0 = bj * 128;

    if (tid < 128) {
        lblA[tid] = labels[rowA0 + tid];
        lblB[tid] = labels[colB0 + tid];
    }

    int lane = tid & 63, warp = tid >> 6;
    int wr = warp >> 1, wc = warp & 1;
    int m_ = lane & 15, g = lane >> 4;

    // staging: lane l -> row l>>2, LDS slot l&3; fetch global chunk (l&3)^((l>>3)&3)
    int r4 = lane >> 2;
    int csw = (lane & 3) ^ ((lane >> 3) & 3);
    const uint8_t* gA0 = rnf8 + (size_t)(rowA0 + warp * 32 + r4) * 1024 + csw * 16;
    const uint8_t* gB0 = rnf8 + (size_t)(colB0 + warp * 32 + r4) * 1024 + csw * 16;

    f32x4 acc[4][4];
#pragma unroll
    for (int a = 0; a < 4; ++a)
#pragma unroll
        for (int b = 0; b < 4; ++b) acc[a][b] = (f32x4){0.f, 0.f, 0.f, 0.f};

    // frag LDS offset: global 16B-chunk g of row r lives at slot g^((r>>1)&3)
    int fsw = (g ^ ((m_ >> 1) & 3)) * 16;

    // prologue: stage kt=0 -> buf0, kt=1 -> buf1 (8 GLD16 in flight)
    GLD16(gA0,       &As[0][(warp * 32) * 64]);
    GLD16(gA0 + 16384, &As[0][(warp * 32 + 16) * 64]);
    GLD16(gB0,       &Bs[0][(warp * 32) * 64]);
    GLD16(gB0 + 16384, &Bs[0][(warp * 32 + 16) * 64]);
    GLD16(gA0 + 64,        &As[1][(warp * 32) * 64]);
    GLD16(gA0 + 64 + 16384, &As[1][(warp * 32 + 16) * 64]);
    GLD16(gB0 + 64,        &Bs[1][(warp * 32) * 64]);
    GLD16(gB0 + 64 + 16384, &Bs[1][(warp * 32 + 16) * 64]);

    // publish label ds_writes at the first barrier
    asm volatile("s_waitcnt lgkmcnt(0)" ::: "memory");

    // K-loop: counted vmcnt(4) — stage(kt) drained, stage(kt+1) in flight.
    for (int kt = 0; kt < 15; ++kt) {
        int cur = kt % 3;
        asm volatile("s_waitcnt vmcnt(4)" ::: "memory");
        __builtin_amdgcn_s_barrier();
        __builtin_amdgcn_sched_barrier(0);
        f32x4 aq[4], bq[4];
#pragma unroll
        for (int ti = 0; ti < 4; ++ti) {
            int rowLoc = wr * 64 + ti * 16 + m_;
            aq[ti] = *(const f32x4*)&As[cur][rowLoc * 64 + fsw];
        }
#pragma unroll
        for (int tj = 0; tj < 4; ++tj) {
            int colLoc = wc * 64 + tj * 16 + m_;
            bq[tj] = *(const f32x4*)&Bs[cur][colLoc * 64 + fsw];
        }
        if (kt < 14) {
            int nxt = (kt + 2) % 3;
            GLD16(gA0 + (kt + 2) * 64,         &As[nxt][(warp * 32) * 64]);
            GLD16(gA0 + (kt + 2) * 64 + 16384, &As[nxt][(warp * 32 + 16) * 64]);
            GLD16(gB0 + (kt + 2) * 64,         &Bs[nxt][(warp * 32) * 64]);
            GLD16(gB0 + (kt + 2) * 64 + 16384, &Bs[nxt][(warp * 32 + 16) * 64]);
        }
#pragma unroll
        for (int s = 0; s < 2; ++s)
#pragma unroll
            for (int ti = 0; ti < 4; ++ti)
#pragma unroll
                for (int tj = 0; tj < 4; ++tj) {
                    i64 a = ((const i64*)&aq[ti])[s];
                    i64 b = ((const i64*)&bq[tj])[s];
                    acc[ti][tj] = __builtin_amdgcn_mfma_f32_16x16x32_fp8_fp8(
                        a, b, acc[ti][tj], 0, 0, 0);
                }
    }
    {   // peeled last step (kt=15): only stage(15) outstanding -> vmcnt(0)
        int cur = 15 % 3;
        asm volatile("s_waitcnt vmcnt(0)" ::: "memory");
        __builtin_amdgcn_s_barrier();
        __builtin_amdgcn_sched_barrier(0);
        f32x4 aq[4], bq[4];
#pragma unroll
        for (int ti = 0; ti < 4; ++ti) {
            int rowLoc = wr * 64 + ti * 16 + m_;
            aq[ti] = *(const f32x4*)&As[cur][rowLoc * 64 + fsw];
        }
#pragma unroll
        for (int tj = 0; tj < 4; ++tj) {
            int colLoc = wc * 64 + tj * 16 + m_;
            bq[tj] = *(const f32x4*)&Bs[cur][colLoc * 64 + fsw];
        }
#pragma unroll
        for (int s = 0; s < 2; ++s)
#pragma unroll
            for (int ti = 0; ti < 4; ++ti)
#pragma unroll
                for (int tj = 0; tj < 4; ++tj) {
                    i64 a = ((const i64*)&aq[ti])[s];
                    i64 b = ((const i64*)&bq[tj])[s];
                    acc[ti][tj] = __builtin_amdgcn_mfma_f32_16x16x32_fp8_fp8(
                        a, b, acc[ti][tj], 0, 0, 0);
                }
    }

    // epilogue: C layout col=lane&15, row=(lane>>4)*4+reg
    bool isDiag = (bi == bj);
    int cl = m_;
    float colE[4] = {0.f, 0.f, 0.f, 0.f}, colP[4] = {0.f, 0.f, 0.f, 0.f};
#pragma unroll
    for (int ti = 0; ti < 4; ++ti) {
        int rowLoc = wr * 64 + ti * 16 + g * 4;
        float rE[4] = {0.f, 0.f, 0.f, 0.f}, rP[4] = {0.f, 0.f, 0.f, 0.f};
        int lr[4];
#pragma unroll
        for (int r = 0; r < 4; ++r) lr[r] = lblA[rowLoc + r];
#pragma unroll
        for (int tj = 0; tj < 4; ++tj) {
            int colLoc = wc * 64 + tj * 16 + cl;
            int gCol = colB0 + colLoc;
            int lc = lblB[colLoc];
            f32x4 a = acc[ti][tj];
#pragma unroll
            for (int r = 0; r < 4; ++r) {
                int gRow = rowA0 + rowLoc + r;
                float z = Z_SCALE * a[r];
                float e = __expf(z);
                bool offd = (gRow != gCol);
                if (!offd) e = 0.f;
                rE[r] += e;
                colE[tj] += e;
                if (offd && (lr[r] == lc)) { rP[r] += z; colP[tj] += z; }
            }
        }
#pragma unroll
        for (int r = 0; r < 4; ++r) {
            float v = rE[r], p = rP[r];
#pragma unroll
            for (int msk = 1; msk < 16; msk <<= 1) {
                v += __shfl_xor(v, msk, 64);
                p += __shfl_xor(p, msk, 64);
            }
            if (cl == 0) {
                int gRow = rowA0 + rowLoc + r;
                atomicAdd(&denom[gRow], v);
                atomicAdd(&posS[gRow], p);
            }
        }
    }
    if (!isDiag) {
#pragma unroll
        for (int tj = 0; tj < 4; ++tj) {
            float v = colE[tj], p = colP[tj];
            v += __shfl_xor(v, 16, 64); p += __shfl_xor(p, 16, 64);
            v += __shfl_xor(v, 32, 64); p += __shfl_xor(p, 32, 64);
            if (g == 0) {
                int gCol = colB0 + wc * 64 + tj * 16 + cl;
                atomicAdd(&denom[gCol], v);
                atomicAdd(&posS[gCol], p);
            }
        }
    }
}

// ---------------- D3: finalize (8 row-blocks + 1 G-block), done-counter -----
__global__ __launch_bounds__(256) void scl_finalize(const float* __restrict__ denom,
                                                    const float* __restrict__ posS,
                                                    const float* __restrict__ W,
                                                    const float* __restrict__ G,
                                                    const int* __restrict__ pwp,
                                                    double* __restrict__ oacc,
                                                    int* __restrict__ done,
                                                    float* __restrict__ out) {
    int t = threadIdx.x;
    __shared__ double wsum[4];
    double contrib = 0.0;

    if (blockIdx.x < 8) {
        int i0 = blockIdx.x * 512 + t;
        float t0 = __logf(denom[i0]) * W[i0] - posS[i0];
        float t1 = __logf(denom[i0 + 256]) * W[i0 + 256] - posS[i0 + 256];
        double td = (double)t0 + (double)t1;
#pragma unroll
        for (int m = 1; m < 64; m <<= 1) td += __shfl_xor(td, m, 64);
        if ((t & 63) == 0) wsum[t >> 6] = td;
        __syncthreads();
        contrib = wsum[0] + wsum[1] + wsum[2] + wsum[3];
    } else {
        int bits = *pwp;
        float pw = (bits >= -(1 << 22) && bits <= (1 << 22)) ? (float)bits
                                                             : __int_as_float(bits);
        const f32x4* G4 = (const f32x4*)G;
        float gs = 0.f;
#pragma unroll
        for (int q = 0; q < 32; ++q) {
            f32x4 v = G4[q * 256 + t];
            gs += v[0] * v[0] + v[1] * v[1] + v[2] * v[2] + v[3] * v[3];
        }
        double gd = (double)gs;
#pragma unroll
        for (int m = 1; m < 64; m <<= 1) gd += __shfl_xor(gd, m, 64);
        if ((t & 63) == 0) wsum[t >> 6] = gd;
        __syncthreads();
        contrib = -(double)(pw * INV_T) * (wsum[0] + wsum[1] + wsum[2] + wsum[3]);
    }

    if (t == 0) {
        atomicAdd(oacc, contrib);
        __threadfence();
        int old = atomicAdd(done, 1);
        if (old == 8) {  // last of 9 blocks
            double tot = atomicAdd(oacc, 0.0);  // coherent read
            out[0] = (float)(tot * (1.0 / 4096.0));
        }
    }
}

// ---------------------------------------------------------------------------
extern "C" void kernel_launch(void* const* d_in, const int* in_sizes, int n_in,
                              void* d_out, int out_size, void* d_ws, size_t ws_size,
                              hipStream_t stream) {
    const float* rep = (const float*)d_in[0];
    const float* sl = (const float*)d_in[1];
    const int* labels = (const int*)d_in[2];
    const int* pwp = (const int*)d_in[3];

    char* ws = (char*)d_ws;
    uint8_t* rnf8 = (uint8_t*)(ws + OFF_RNF8);
    float* denom = (float*)(ws + OFF_DENOM);
    float* posS = (float*)(ws + OFF_POSS);
    float* G = (float*)(ws + OFF_G);
    double* oacc = (double*)(ws + OFF_OACC);
    int* done = (int*)(ws + OFF_DONE);
    float* cs_part = (float*)(ws + OFF_CSP);
    int* cc_part = (int*)(ws + OFF_CCP);
    float* W = (float*)(ws + OFF_W);

    scl_stage1<<<4169, 256, 0, stream>>>(rep, sl, labels, (uint32_t*)rnf8,
                                         cs_part, cc_part, ws + OFF_DENOM);
    scl_gw<<<N_G + N_W, 256, 0, stream>>>(rnf8, sl, labels, cs_part, cc_part,
                                          pwp, G, W);
    scl_gemm<<<N_GEMM, 256, 0, stream>>>(rnf8, labels, denom, posS);
    scl_finalize<<<9, 256, 0, stream>>>(denom, posS, W, G, pwp, oacc, done,
                                        (float*)d_out);
}